// Round 4
// baseline (279.451 us; speedup 1.0000x reference)
//
#include <hip/hip_runtime.h>
#include <math.h>

#define HH 1536
#define WW 1536
#define HWSZ (HH*WW)
#define NT 384   // one row per block: 384 threads x 4 px = 1536

__device__ __forceinline__ float4 LD4(const float* __restrict__ p, int row, int t) {
    return reinterpret_cast<const float4*>(p + row)[t];
}

__global__ __launch_bounds__(NT) void step_kernel(
    const float* __restrict__ phi,
    const float* __restrict__ sensory,
    const float* __restrict__ gamma,
    const float* __restrict__ alpha,
    const float* __restrict__ mixw,
    float* __restrict__ out,
    float* __restrict__ sums)
{
    // wdt[o][c] = dt_o * ( eps_o*mix[o][c] + S2F*0.2*[o<5 && c>=5] + F2S*0.2*[o>=5 && c<5] )
    __shared__ float s_wdt[100];
    __shared__ float s_g[10];
    __shared__ float s_a0;
    __shared__ float s_red[6][10];

    const int tid = threadIdx.x;
    if (tid < 100) {
        const int o = tid / 10;
        const int c = tid % 10;
        const float eps  = (o < 5) ? 0.06f : 0.02f;
        const float dt_o = (o < 5) ? 0.02f : 0.004f;
        float w = eps * mixw[tid];
        if (o < 5 && c >= 5) w += 0.02f * 0.2f;   // S2F * (1/5)
        if (o >= 5 && c < 5) w += 0.04f * 0.2f;   // F2S * (1/5)
        s_wdt[tid] = dt_o * w;
    }
    if (tid < 10)  s_g[tid] = gamma[tid];
    if (tid == 0)  s_a0     = alpha[0];
    __syncthreads();

    // XCD-banded swizzle: contiguous 192-row band per XCD for L2 row-reuse.
    const int blk = blockIdx.x;
    const int y = (blk & 7) * 192 + (blk >> 3);

    const int x0 = tid * 4;

    const int ym1 = (y == 0)      ? HH - 1     : y - 1;
    const int yp1 = (y == HH - 1) ? 0          : y + 1;
    const int ym2 = (y < 2)       ? y + HH - 2 : y - 2;
    const int yp2 = (y >= HH - 2) ? y - HH + 2 : y + 2;

    const int r0  = y   * WW;
    const int rm1 = ym1 * WW;
    const int rp1 = yp1 * WW;
    const int rm2 = ym2 * WW;
    const int rp2 = yp2 * WW;

    const int xl1 = (x0 == 0)        ? WW - 1 : x0 - 1;
    const int xl2 = (x0 == 0)        ? WW - 2 : x0 - 2;
    const int xr1 = (x0 + 4 == WW)   ? 0      : x0 + 4;
    const int xr2 = (x0 + 4 == WW)   ? 1      : x0 + 5;

    // pn accumulators — the ONLY persistent per-channel state (40 VGPRs).
    float pn[10][4];
    #pragma unroll
    for (int o = 0; o < 10; ++o)
        #pragma unroll
        for (int k = 0; k < 4; ++k) pn[o][k] = 0.0f;

    #pragma unroll
    for (int c = 0; c < 10; ++c) {
        const float* pc = phi + (size_t)c * HWSZ;
        const float4 cm = LD4(pc, r0,  tid);
        const float4 nn = LD4(pc, rm1, tid);
        const float4 ss = LD4(pc, rp1, tid);
        const float wl1 = pc[r0 + xl1];
        const float wr1 = pc[r0 + xr1];

        float pvk[4] = {cm.x, cm.y, cm.z, cm.w};

        float lap[4];
        lap[0] = nn.x + ss.x + wl1  + cm.y - 4.0f * cm.x;
        lap[1] = nn.y + ss.y + cm.x + cm.z - 4.0f * cm.y;
        lap[2] = nn.z + ss.z + cm.y + cm.w - 4.0f * cm.z;
        lap[3] = nn.w + ss.w + cm.z + wr1  - 4.0f * cm.w;

        float bl[4] = {0.f, 0.f, 0.f, 0.f};
        if (c == 0 || c == 3 || c == 4 || c == 9) {
            // direct 13-pt bilaplacian: 20c -8(N+S+W+E) +2(diag) + (NN+SS+WW+EE)
            const float4 t2n = LD4(pc, rm2, tid);
            const float4 t2s = LD4(pc, rp2, tid);
            const float wl2 = pc[r0  + xl2];
            const float wr2 = pc[r0  + xr2];
            const float nwl = pc[rm1 + xl1];
            const float ner = pc[rm1 + xr1];
            const float swl = pc[rp1 + xl1];
            const float ser = pc[rp1 + xr1];
            bl[0] = 20.0f*cm.x - 8.0f*(nn.x + ss.x + wl1  + cm.y)
                  + 2.0f*(nwl  + nn.y + swl  + ss.y) + (t2n.x + t2s.x + wl2  + cm.z);
            bl[1] = 20.0f*cm.y - 8.0f*(nn.y + ss.y + cm.x + cm.z)
                  + 2.0f*(nn.x + nn.z + ss.x + ss.z) + (t2n.y + t2s.y + wl1  + cm.w);
            bl[2] = 20.0f*cm.z - 8.0f*(nn.z + ss.z + cm.y + cm.w)
                  + 2.0f*(nn.y + nn.w + ss.y + ss.w) + (t2n.z + t2s.z + cm.x + wr1);
            bl[3] = 20.0f*cm.w - 8.0f*(nn.w + ss.w + cm.z + wr1)
                  + 2.0f*(nn.z + ner  + ss.z + ser ) + (t2n.w + t2s.w + cm.y + wr2);
        }

        const float dtc = (c < 5) ? 0.02f : 0.004f;

        #pragma unroll
        for (int k = 0; k < 4; ++k) {
            const float pp = pvk[k];
            const float lv = lap[k];
            const float bv = bl[k];
            float dd;
            switch (c) {
            case 0: dd = -s_g[0]*lv - s_a0*pp*pp*pp + 0.12f*bv; break;
            case 1: dd = -s_g[1]*lv + 0.15f*__sinf(pp) + 0.08f*pp*pp*pp; break;
            case 2: dd = -s_g[2]*lv + 0.2f*pp*(1.0f - pp*pp); break;
            case 3: { const float p2 = pp*pp;
                      dd = -s_g[3]*lv - 0.03f*p2*p2*pp + 0.08f*bv; } break;
            case 4: dd = -s_g[4]*lv + 0.12f*pp*__logf(fabsf(pp) + 1e-6f) + 0.02f*bv; break;
            case 5: { const float p2 = pp*pp;
                      dd = -s_g[5]*lv + 0.08f*p2*pp - 0.02f*p2*p2*pp; } break;
            case 6: { const float p2 = pp*pp;
                      dd = -s_g[6]*lv + 0.06f*p2*p2 - 0.04f*pp; } break;
            case 7: { const float pc7 = fminf(fmaxf(pp, -2.0f), 2.0f);
                      dd = -s_g[7]*lv + 0.04f*(__expf(pc7) - __expf(-pc7)); } break;
            case 8: dd = -s_g[8]*lv + 0.05f*pp*pp - 0.08f*pp; break;
            default: { const float p3 = pp*pp*pp;
                       dd = -s_g[9]*lv + 0.02f*p3*p3 - 0.04f*p3 + 0.01f*bv; } break;
            }
            // own-channel: + pv + dt_c * dphi_c
            pn[c][k] += pp + dtc * dd;
        }

        // linear coupling (mix + inter-band means), dt-prescaled
        #pragma unroll
        for (int o = 0; o < 10; ++o) {
            const float w = s_wdt[o*10 + c];
            #pragma unroll
            for (int k = 0; k < 4; ++k) pn[o][k] = fmaf(w, pvk[k], pn[o][k]);
        }
        // pvk, lap, bl, dd all dead here — registers recycle for next channel.
    }

    // sensory terms + clip
    {
        const float4 sd4 = LD4(sensory, r0, tid);
        const float sdk[4] = {sd4.x, sd4.y, sd4.z, sd4.w};
        #pragma unroll
        for (int k = 0; k < 4; ++k) {
            pn[0][k] += 0.02f  * (0.2f  * sdk[k]);
            pn[4][k] += 0.02f  * (0.08f * fabsf(sdk[k]));
            pn[9][k] += 0.004f * (0.05f * sdk[k]);
        }
    }

    const int lane = tid & 63;
    const int wave = tid >> 6;

    #pragma unroll
    for (int o = 0; o < 10; ++o) {
        float4 o4;
        float* pk = pn[o];
        o4.x = fminf(fmaxf(pk[0], -4.0f), 4.0f);
        o4.y = fminf(fmaxf(pk[1], -4.0f), 4.0f);
        o4.z = fminf(fmaxf(pk[2], -4.0f), 4.0f);
        o4.w = fminf(fmaxf(pk[3], -4.0f), 4.0f);
        reinterpret_cast<float4*>(out + (size_t)o * HWSZ + r0)[tid] = o4;

        float s = o4.x + o4.y + o4.z + o4.w;
        #pragma unroll
        for (int off = 32; off > 0; off >>= 1) s += __shfl_down(s, off, 64);
        if (lane == 0) s_red[wave][o] = s;
    }

    __syncthreads();
    if (tid < 10) {
        float v = 0.0f;
        #pragma unroll
        for (int w = 0; w < 6; ++w) v += s_red[w][tid];
        atomicAdd(&sums[tid], v);
    }
}

__global__ void finalize_kernel(const float* __restrict__ sums,
                                float* __restrict__ out)
{
    const int t = threadIdx.x;
    const float inv = 1.0f / (float)HWSZ;
    const size_t base = (size_t)10 * HWSZ;
    if (t == 0) out[base]     = sums[0] * inv;  // phi1_mean (channel 0)
    if (t == 1) out[base + 1] = sums[4] * inv;  // phi5_mean (channel 4)
    if (t >= 2 && t < 12) out[base + 2 + (t - 2)] = sums[t - 2] * inv;  // field_means
}

extern "C" void kernel_launch(void* const* d_in, const int* in_sizes, int n_in,
                              void* d_out, int out_size, void* d_ws, size_t ws_size,
                              hipStream_t stream) {
    const float* phi     = (const float*)d_in[0];
    const float* sensory = (const float*)d_in[1];
    const float* gamma   = (const float*)d_in[2];
    const float* alpha   = (const float*)d_in[3];
    const float* mixw    = (const float*)d_in[4];
    float* out = (float*)d_out;
    float* sums = (float*)d_ws;

    hipMemsetAsync(sums, 0, 10 * sizeof(float), stream);

    step_kernel<<<dim3(HH), NT, 0, stream>>>(phi, sensory, gamma, alpha, mixw, out, sums);
    finalize_kernel<<<1, 64, 0, stream>>>(sums, out);
}

// Round 5
// 262.086 us; speedup vs baseline: 1.0663x; 1.0663x over previous
//
#include <hip/hip_runtime.h>
#include <math.h>

#define HH 1536
#define WW 1536
#define HWSZ (HH*WW)
#define NT 384   // 384 threads x 2 px = 768 px = half a row per block

__device__ __forceinline__ float2 LD2(const float* __restrict__ p, int row, int t2) {
    return reinterpret_cast<const float2*>(p + row)[t2];
}

__global__ __launch_bounds__(NT) void step_kernel(
    const float* __restrict__ phi,
    const float* __restrict__ sensory,
    const float* __restrict__ gamma,
    const float* __restrict__ alpha,
    const float* __restrict__ mixw,
    float* __restrict__ out,
    float* __restrict__ sums)
{
    __shared__ float s_mix[100];
    __shared__ float s_g[10];
    __shared__ float s_a0;
    __shared__ float s_red[6][10];

    const int tid = threadIdx.x;
    if (tid < 100) s_mix[tid] = mixw[tid];
    if (tid < 10)  s_g[tid]   = gamma[tid];
    if (tid == 0)  s_a0       = alpha[0];
    __syncthreads();

    // XCD-banded swizzle: 3072 blocks; each XCD gets a contiguous 192-row band.
    const int id  = blockIdx.x;
    const int xcd = id & 7;
    const int u   = id >> 3;          // 0..383
    const int y    = xcd * 192 + (u >> 1);
    const int half = u & 1;

    const int x0 = half * 768 + tid * 2;   // even, 0..1534
    const int t2 = x0 >> 1;                // float2 index within row

    const int ym1 = (y == 0)      ? HH - 1     : y - 1;
    const int yp1 = (y == HH - 1) ? 0          : y + 1;
    const int ym2 = (y < 2)       ? y + HH - 2 : y - 2;
    const int yp2 = (y >= HH - 2) ? y - HH + 2 : y + 2;

    const int r0  = y   * WW;
    const int rm1 = ym1 * WW;
    const int rp1 = yp1 * WW;
    const int rm2 = ym2 * WW;
    const int rp2 = yp2 * WW;

    const int xl1 = (x0 == 0)      ? WW - 1 : x0 - 1;
    const int xl2 = (x0 == 0)      ? WW - 2 : x0 - 2;
    const int xr1 = (x0 + 2 == WW) ? 0      : x0 + 2;
    const int xr2 = (x0 + 2 == WW) ? 1      : x0 + 3;

    float pv[10][2];   // phi center values (for coupling, epilogue)
    float dv[10][2];   // per-channel dphi (nonlinear + lap/bilap part)

    #pragma unroll
    for (int c = 0; c < 10; ++c) {
        const float* pc = phi + (size_t)c * HWSZ;
        const float2 cm = LD2(pc, r0,  t2);
        const float2 nn = LD2(pc, rm1, t2);
        const float2 ss = LD2(pc, rp1, t2);
        const float wl1 = pc[r0 + xl1];
        const float wr1 = pc[r0 + xr1];

        float lap[2];
        lap[0] = nn.x + ss.x + wl1  + cm.y - 4.0f * cm.x;
        lap[1] = nn.y + ss.y + cm.x + wr1  - 4.0f * cm.y;

        float bl[2] = {0.f, 0.f};
        if (c == 0 || c == 3 || c == 4 || c == 9) {
            // direct 13-pt bilaplacian: 20c -8(N+S+W+E) +2(diag) + (NN+SS+WW+EE)
            const float2 t2n = LD2(pc, rm2, t2);
            const float2 t2s = LD2(pc, rp2, t2);
            const float wl2 = pc[r0  + xl2];
            const float wr2 = pc[r0  + xr2];
            const float nwl = pc[rm1 + xl1];
            const float ner = pc[rm1 + xr1];
            const float swl = pc[rp1 + xl1];
            const float ser = pc[rp1 + xr1];
            bl[0] = 20.0f*cm.x - 8.0f*(nn.x + ss.x + wl1  + cm.y)
                  + 2.0f*(nwl  + nn.y + swl  + ss.y) + (t2n.x + t2s.x + wl2 + wr1);
            bl[1] = 20.0f*cm.y - 8.0f*(nn.y + ss.y + cm.x + wr1)
                  + 2.0f*(nn.x + ner  + ss.x + ser ) + (t2n.y + t2s.y + wl1 + wr2);
        }

        pv[c][0] = cm.x; pv[c][1] = cm.y;

        #pragma unroll
        for (int k = 0; k < 2; ++k) {
            const float pp = pv[c][k];
            const float lv = lap[k];
            const float bv = bl[k];
            float dd;
            switch (c) {
            case 0: dd = -s_g[0]*lv - s_a0*pp*pp*pp + 0.12f*bv; break;
            case 1: dd = -s_g[1]*lv + 0.15f*__sinf(pp) + 0.08f*pp*pp*pp; break;
            case 2: dd = -s_g[2]*lv + 0.2f*pp*(1.0f - pp*pp); break;
            case 3: { const float p2 = pp*pp;
                      dd = -s_g[3]*lv - 0.03f*p2*p2*pp + 0.08f*bv; } break;
            case 4: dd = -s_g[4]*lv + 0.12f*pp*__logf(fabsf(pp) + 1e-6f) + 0.02f*bv; break;
            case 5: { const float p2 = pp*pp;
                      dd = -s_g[5]*lv + 0.08f*p2*pp - 0.02f*p2*p2*pp; } break;
            case 6: { const float p2 = pp*pp;
                      dd = -s_g[6]*lv + 0.06f*p2*p2 - 0.04f*pp; } break;
            case 7: { const float pc7 = fminf(fmaxf(pp, -2.0f), 2.0f);
                      dd = -s_g[7]*lv + 0.04f*(__expf(pc7) - __expf(-pc7)); } break;
            case 8: dd = -s_g[8]*lv + 0.05f*pp*pp - 0.08f*pp; break;
            default: { const float p3 = pp*pp*pp;
                       dd = -s_g[9]*lv + 0.02f*p3*p3 - 0.04f*p3 + 0.01f*bv; } break;
            }
            dv[c][k] = dd;
        }
    }

    float fmv[2], smv[2], sdk[2];
    {
        const float2 sd2 = LD2(sensory, r0, t2);
        sdk[0] = sd2.x; sdk[1] = sd2.y;
        #pragma unroll
        for (int k = 0; k < 2; ++k) {
            fmv[k] = (pv[0][k] + pv[1][k] + pv[2][k] + pv[3][k] + pv[4][k]) * 0.2f;
            smv[k] = (pv[5][k] + pv[6][k] + pv[7][k] + pv[8][k] + pv[9][k]) * 0.2f;
        }
    }

    const int lane = tid & 63;
    const int wave = tid >> 6;

    #pragma unroll
    for (int o = 0; o < 10; ++o) {
        float pn[2];
        #pragma unroll
        for (int k = 0; k < 2; ++k) {
            float cp = 0.0f;
            #pragma unroll
            for (int c = 0; c < 10; ++c) cp = fmaf(s_mix[o*10 + c], pv[c][k], cp);
            float dd = dv[o][k];
            if (o < 5) {
                dd += 0.06f * cp + 0.02f * smv[k];          // EPS_FAST, S2F
                if (o == 0) dd += 0.2f  * sdk[k];
                if (o == 4) dd += 0.08f * fabsf(sdk[k]);
                pn[k] = pv[o][k] + 0.02f * dd;              // DT * FAST_DT
            } else {
                dd += 0.02f * cp + 0.04f * fmv[k];          // EPS_SLOW, F2S
                if (o == 9) dd += 0.05f * sdk[k];
                pn[k] = pv[o][k] + 0.004f * dd;             // DT * SLOW_DT
            }
            pn[k] = fminf(fmaxf(pn[k], -4.0f), 4.0f);
        }
        float2 o2; o2.x = pn[0]; o2.y = pn[1];
        reinterpret_cast<float2*>(out + (size_t)o * HWSZ + r0)[t2] = o2;

        float s = pn[0] + pn[1];
        #pragma unroll
        for (int off = 32; off > 0; off >>= 1) s += __shfl_down(s, off, 64);
        if (lane == 0) s_red[wave][o] = s;
    }

    __syncthreads();
    if (tid < 10) {
        float v = 0.0f;
        #pragma unroll
        for (int w = 0; w < 6; ++w) v += s_red[w][tid];
        atomicAdd(&sums[tid], v);
    }
}

__global__ void finalize_kernel(const float* __restrict__ sums,
                                float* __restrict__ out)
{
    const int t = threadIdx.x;
    const float inv = 1.0f / (float)HWSZ;
    const size_t base = (size_t)10 * HWSZ;
    if (t == 0) out[base]     = sums[0] * inv;  // phi1_mean (channel 0)
    if (t == 1) out[base + 1] = sums[4] * inv;  // phi5_mean (channel 4)
    if (t >= 2 && t < 12) out[base + 2 + (t - 2)] = sums[t - 2] * inv;  // field_means
}

extern "C" void kernel_launch(void* const* d_in, const int* in_sizes, int n_in,
                              void* d_out, int out_size, void* d_ws, size_t ws_size,
                              hipStream_t stream) {
    const float* phi     = (const float*)d_in[0];
    const float* sensory = (const float*)d_in[1];
    const float* gamma   = (const float*)d_in[2];
    const float* alpha   = (const float*)d_in[3];
    const float* mixw    = (const float*)d_in[4];
    float* out = (float*)d_out;
    float* sums = (float*)d_ws;

    hipMemsetAsync(sums, 0, 10 * sizeof(float), stream);

    step_kernel<<<dim3(HH * 2), NT, 0, stream>>>(phi, sensory, gamma, alpha, mixw, out, sums);
    finalize_kernel<<<1, 64, 0, stream>>>(sums, out);
}